// Round 9
// baseline (323.187 us; speedup 1.0000x reference)
//
#include <hip/hip_runtime.h>
#include <cstdint>

// Problem constants: B=2, S=2048, D=2048, H=16, DH=128
typedef unsigned short u16;
typedef __attribute__((ext_vector_type(8))) short short8v;       // 8 x bf16 (MFMA A/B frag)
typedef __attribute__((ext_vector_type(8))) unsigned short u16x8;
typedef __attribute__((ext_vector_type(4))) float floatx4;       // MFMA C/D frag

typedef unsigned int __attribute__((address_space(1))) as1_u32;
typedef unsigned int __attribute__((address_space(3))) as3_u32;

__device__ __forceinline__ u16 f2bf(float f) {
  union { float f; unsigned u; } v; v.f = f;
  unsigned r = v.u + 0x7FFFu + ((v.u >> 16) & 1u);   // RNE
  return (u16)(r >> 16);
}

__device__ __forceinline__ unsigned cvt_pk_bf16(float lo, float hi) {
  unsigned r;
  asm("v_cvt_pk_bf16_f32 %0, %1, %2" : "=v"(r) : "v"(lo), "v"(hi));
  return r;
}

__device__ __forceinline__ void gload16(void* lds, const void* g) {
  __builtin_amdgcn_global_load_lds((as1_u32*)(uintptr_t)g, (as3_u32*)(uintptr_t)lds, 16, 0, 0);
}

// ---------------- fp32 -> bf16 conversion ----------------
__global__ __launch_bounds__(256) void f2bf_kernel(const float* __restrict__ in,
                                                   u16* __restrict__ out, int n4) {
  int i = blockIdx.x * 256 + threadIdx.x;
  const int stride = gridDim.x * 256;
  for (; i < n4; i += stride) {
    float4 v = ((const float4*)in)[i];
    ushort4 o;
    o.x = f2bf(v.x); o.y = f2bf(v.y); o.z = f2bf(v.z); o.w = f2bf(v.w);
    ((ushort4*)out)[i] = o;
  }
}

// ---------------- 128x256 BK=32 GEMM, 512 thr, 3-slot, 2 blocks/CU (QKV) ----------
template <int OUT_BF16>
__global__ __launch_bounds__(512, 4)
void gemm_v4(const u16* __restrict__ A, const u16* __restrict__ B,
             const float* __restrict__ bias, void* __restrict__ C,
             int M, int N, int K) {
  __shared__ u16 Al[3][4096];   // 24KB
  __shared__ u16 Bl[3][8192];   // 48KB
  const int tid = threadIdx.x;
  const int wid = tid >> 6, lane = tid & 63;
  const int wr = wid >> 2, wc = wid & 3;
  const int li = lane & 15, lg = lane >> 4;
  const int nwg = gridDim.x;
  const int bid = blockIdx.x;
  const int swz = (bid & 7) * (nwg >> 3) + (bid >> 3);   // XCD-bijective (nwg%8==0)
  const int mcnt = M >> 7;
  const int bm = swz % mcnt, bn = swz / mcnt;            // bm-fastest: B-panels L2-hot
  const int brow = bm * 128, bcol = bn * 256;
  const int NT = K >> 5;                                 // BK=32

  const int P = tid * 16;
  const int pr = P >> 7;
  const int innerLog = (P & 127) ^ ((pr & 7) << 4);
  const int srow = (pr << 1) + (innerLog >> 6);
  const int skb = innerLog & 63;
  const u16* aS = A + (size_t)(brow + srow) * K + (skb >> 1);
  const u16* bS = B + (size_t)(bcol + srow) * K + (skb >> 1);

#define STG(slot, kt_)                                                          \
  {                                                                             \
    const u16* a_ = aS + (kt_) * 32;                                            \
    const u16* b_ = bS + (kt_) * 32;                                            \
    gload16((char*)&Al[slot][0] + P, a_);                                       \
    gload16((char*)&Bl[slot][0] + P, b_);                                       \
    gload16((char*)&Bl[slot][0] + 8192 + P, b_ + (size_t)128 * K);              \
  }

  floatx4 acc[4][4];
#pragma unroll
  for (int m = 0; m < 4; ++m)
#pragma unroll
    for (int n = 0; n < 4; ++n) acc[m][n] = floatx4{0.f, 0.f, 0.f, 0.f};

  const int fxor = ((li >> 1) & 7) << 4;
  const int finner = (((li & 1) << 6) + (lg << 4)) ^ fxor;
  const int aoff = (wr * 32 + (li >> 1)) * 128 + finner;
  const int boff = (wc * 32 + (li >> 1)) * 128 + finner;

  STG(0, 0);
  STG(1, 1);
  asm volatile("s_waitcnt vmcnt(3)" ::: "memory");
  __builtin_amdgcn_s_barrier();

  int sl = 0;
  for (int t = 0; t < NT; ++t) {
    const char* Ab = (const char*)&Al[sl][0];
    const char* Bb = (const char*)&Bl[sl][0];
    short8v af[4], bf[4];
#pragma unroll
    for (int m = 0; m < 4; ++m) af[m] = *(const short8v*)(Ab + aoff + m * 1024);
#pragma unroll
    for (int n = 0; n < 4; ++n) bf[n] = *(const short8v*)(Bb + boff + n * 1024);

    int s2 = sl + 2; if (s2 >= 3) s2 -= 3;
    if (t + 2 < NT) STG(s2, t + 2);

    __builtin_amdgcn_s_setprio(1);
#pragma unroll
    for (int m = 0; m < 4; ++m)
#pragma unroll
      for (int n = 0; n < 4; ++n)
        acc[m][n] = __builtin_amdgcn_mfma_f32_16x16x32_bf16(af[m], bf[n], acc[m][n], 0, 0, 0);
    __builtin_amdgcn_s_setprio(0);

    if (t + 2 < NT)      asm volatile("s_waitcnt vmcnt(3)" ::: "memory");
    else if (t + 1 < NT) asm volatile("s_waitcnt vmcnt(0)" ::: "memory");
    __builtin_amdgcn_s_barrier();
    sl = (sl + 1 == 3) ? 0 : sl + 1;
  }
#undef STG

  const int crow0 = brow + wr * 64 + lg * 4;
  const int ccol0 = bcol + wc * 64 + li;
#pragma unroll
  for (int n = 0; n < 4; ++n) {
    const float bv = bias[ccol0 + n * 16];
#pragma unroll
    for (int m = 0; m < 4; ++m) {
#pragma unroll
      for (int j = 0; j < 4; ++j) {
        const float v = acc[m][n][j] + bv;
        const size_t idx = (size_t)(crow0 + m * 16 + j) * N + (ccol0 + n * 16);
        if (OUT_BF16) ((u16*)C)[idx] = f2bf(v);
        else          ((float*)C)[idx] = v;
      }
    }
  }
}

// ---------------- 128x128 BK=32 GEMM, 256 thr, 3-slot, 3 blocks/CU (out-proj) ------
// 4 waves (2M x 2N), wave tile 64x64. LDS 48KB -> 3 blocks/CU: independent
// barrier domains interleave LDS/MFMA bursts. Same super-row swizzle; second
// half-tile source = +64*K (swizzle invariant under +64 rows).
// Ledger (4 loads/stage): prologue t0,t1 -> vmcnt(4); per tile: {8 ds_read;
// stage t+2; 16 MFMA; vmcnt(4); barrier} — never 0 mid-loop.
template <int OUT_BF16>
__global__ __launch_bounds__(256, 4)
void gemm_s(const u16* __restrict__ A, const u16* __restrict__ B,
            const float* __restrict__ bias, void* __restrict__ C,
            int M, int N, int K) {
  __shared__ u16 Al[3][4096];   // 24KB
  __shared__ u16 Bl[3][4096];   // 24KB
  const int tid = threadIdx.x;
  const int wid = tid >> 6, lane = tid & 63;
  const int wr = wid >> 1, wc = wid & 1;
  const int li = lane & 15, lg = lane >> 4;
  const int nwg = gridDim.x;
  const int bid = blockIdx.x;
  const int swz = (bid & 7) * (nwg >> 3) + (bid >> 3);   // XCD-bijective
  const int mcnt = M >> 7;
  const int bm = swz % mcnt, bn = swz / mcnt;
  const int brow = bm * 128, bcol = bn * 128;
  const int NT = K >> 5;

  const int P = tid * 16;                                 // 0..4095
  const int pr = P >> 7;
  const int innerLog = (P & 127) ^ ((pr & 7) << 4);
  const int srow = (pr << 1) + (innerLog >> 6);           // 0..63
  const int skb = innerLog & 63;
  const u16* aS = A + (size_t)(brow + srow) * K + (skb >> 1);
  const u16* bS = B + (size_t)(bcol + srow) * K + (skb >> 1);

#define STG(slot, kt_)                                                          \
  {                                                                             \
    const u16* a_ = aS + (kt_) * 32;                                            \
    const u16* b_ = bS + (kt_) * 32;                                            \
    gload16((char*)&Al[slot][0] + P, a_);                                       \
    gload16((char*)&Al[slot][0] + 4096 + P, a_ + (size_t)64 * K);               \
    gload16((char*)&Bl[slot][0] + P, b_);                                       \
    gload16((char*)&Bl[slot][0] + 4096 + P, b_ + (size_t)64 * K);               \
  }

  floatx4 acc[4][4];
#pragma unroll
  for (int m = 0; m < 4; ++m)
#pragma unroll
    for (int n = 0; n < 4; ++n) acc[m][n] = floatx4{0.f, 0.f, 0.f, 0.f};

  const int fxor = ((li >> 1) & 7) << 4;
  const int finner = (((li & 1) << 6) + (lg << 4)) ^ fxor;
  const int aoff = (wr * 32 + (li >> 1)) * 128 + finner;
  const int boff = (wc * 32 + (li >> 1)) * 128 + finner;

  STG(0, 0);
  STG(1, 1);
  asm volatile("s_waitcnt vmcnt(4)" ::: "memory");
  __builtin_amdgcn_s_barrier();

  int sl = 0;
  for (int t = 0; t < NT; ++t) {
    const char* Ab = (const char*)&Al[sl][0];
    const char* Bb = (const char*)&Bl[sl][0];
    short8v af[4], bf[4];
#pragma unroll
    for (int m = 0; m < 4; ++m) af[m] = *(const short8v*)(Ab + aoff + m * 1024);
#pragma unroll
    for (int n = 0; n < 4; ++n) bf[n] = *(const short8v*)(Bb + boff + n * 1024);

    int s2 = sl + 2; if (s2 >= 3) s2 -= 3;
    if (t + 2 < NT) STG(s2, t + 2);

    __builtin_amdgcn_s_setprio(1);
#pragma unroll
    for (int m = 0; m < 4; ++m)
#pragma unroll
      for (int n = 0; n < 4; ++n)
        acc[m][n] = __builtin_amdgcn_mfma_f32_16x16x32_bf16(af[m], bf[n], acc[m][n], 0, 0, 0);
    __builtin_amdgcn_s_setprio(0);

    if (t + 2 < NT)      asm volatile("s_waitcnt vmcnt(4)" ::: "memory");
    else if (t + 1 < NT) asm volatile("s_waitcnt vmcnt(0)" ::: "memory");
    __builtin_amdgcn_s_barrier();
    sl = (sl + 1 == 3) ? 0 : sl + 1;
  }
#undef STG

  const int crow0 = brow + wr * 64 + lg * 4;
  const int ccol0 = bcol + wc * 64 + li;
#pragma unroll
  for (int n = 0; n < 4; ++n) {
    const float bv = bias[ccol0 + n * 16];
#pragma unroll
    for (int m = 0; m < 4; ++m) {
#pragma unroll
      for (int j = 0; j < 4; ++j) {
        const float v = acc[m][n][j] + bv;
        const size_t idx = (size_t)(crow0 + m * 16 + j) * N + (ccol0 + n * 16);
        if (OUT_BF16) ((u16*)C)[idx] = f2bf(v);
        else          ((float*)C)[idx] = v;
      }
    }
  }
}

// ---------------- V transpose: qkv V-part [b,s,h,dh] -> vt [b,h,dh,s] ----------------
__global__ __launch_bounds__(256)
void transpose_v(const u16* __restrict__ qkv, u16* __restrict__ vt) {
  __shared__ u16 T[64][136];
  const int st = blockIdx.x, bh = blockIdx.y;
  const int b = bh >> 4, h = bh & 15;
  const int tid = threadIdx.x;
  const u16* src = qkv + (size_t)(b * 2048 + st * 64) * 6144 + 4096 + h * 128;
  u16* dst = vt + (size_t)bh * 128 * 2048 + st * 64;
#pragma unroll
  for (int p = 0; p < 4; ++p) {
    const int e = (p * 256 + tid) * 8;
    const int r = e >> 7, c = e & 127;
    *(u16x8*)&T[r][c] = *(const u16x8*)&src[(size_t)r * 6144 + c];
  }
  __syncthreads();
#pragma unroll
  for (int p = 0; p < 4; ++p) {
    const int e = (p * 256 + tid) * 8;
    const int dh = e >> 6, s0 = e & 63;
    u16x8 o;
#pragma unroll
    for (int j = 0; j < 8; ++j) o[j] = T[s0 + j][dh];
    *(u16x8*)&dst[(size_t)dh * 2048 + s0] = o;
  }
}

// ---------------- fused causal flash attention: 512 thr, 8 waves x 16 q-rows ------
// Swapped QK^T + in-register softmax; halved per-wave serial softmax vs the
// 4-wave version, 2x TLP (16 waves/CU). Ledger (2 loads/stage):
// top: issue K(t+1) -> vmcnt(4) [drains K(t)]; last tile vmcnt(2).
// mid: vmcnt(2) [drains V(t)]; last tile vmcnt(0). V(t+1) staged after bar3.
__global__ __launch_bounds__(512, 2)
void attn_fused(const u16* __restrict__ qkv, const u16* __restrict__ vt,
                const int* __restrict__ kpm, u16* __restrict__ attn_out) {
  constexpr int S = 2048, DQ = 6144;
  __shared__ u16 Kl[2][64 * 128];   // 32KB, dbuf; reused as O-staging (8x4KB)
  __shared__ u16 Vl[128 * 64];      // 16KB
  __shared__ u16 msk[2048];         // 4KB validity flags
  __shared__ int s_any;
  const int bx = blockIdx.x, by = blockIdx.y;
  const int qt = ((by >> 4) & 1) ? bx : (15 - bx);   // co-resident qt balance
  const int bh = by;
  const int b = bh >> 4, h = bh & 15;
  const int tid = threadIdx.x, wave = tid >> 6, lane = tid & 63;
  const int lg = lane >> 4, li = lane & 15;
  const int qrow0 = qt * 128 + wave * 16;

  const u16* Qb = qkv + (size_t)b * S * DQ + h * 128;
  const u16* Kb = Qb + 2048;
  const u16* Vtb = vt + (size_t)bh * 128 * 2048;
  const int* mrow = kpm + b * S;

  if (tid == 0) s_any = 0;
  __syncthreads();
  {
    int a = 0;
    for (int j = tid; j < 2048; j += 512) {
      const int mv = mrow[j];
      msk[j] = (u16)(mv != 0);
      if (mv && j <= qt * 128) a = 1;
    }
    if (a) s_any = 1;
  }
  __syncthreads();
  const int anyv = s_any;
  const int nt = anyv ? (2 * qt + 2) : 32;
  const int causalFromW = anyv ? (qrow0 >> 6) : 0;

  // Q as B-fragment (single 16-row group per wave)
  short8v qb[4];
  {
    const u16* qp = Qb + (size_t)(qrow0 + li) * DQ + lg * 8;
#pragma unroll
    for (int kk = 0; kk < 4; ++kk) qb[kk] = *(const short8v*)(qp + kk * 32);
  }
  asm volatile("s_waitcnt vmcnt(0)" ::: "memory");  // clean VMEM ledger

  float mM = -3.0e38f, lSum = 0.f;
  floatx4 oa[8];
#pragma unroll
  for (int n = 0; n < 8; ++n) oa[n] = floatx4{0.f, 0.f, 0.f, 0.f};

  // pre-swizzled staging sources (XOR involution on bits 4-6 within a row)
  const u16* kSrc[2]; const u16* vSrc[2];
#pragma unroll
  for (int i = 0; i < 2; ++i) {
    const int L = i * 8192 + tid * 16;
    const int r = L >> 8;
    const int c = ((L & 255) ^ ((r & 7) << 4)) >> 1;
    kSrc[i] = Kb + (size_t)r * DQ + c;
    const int d = L >> 7;
    const int sv = ((L & 127) ^ ((d & 7) << 4)) >> 1;
    vSrc[i] = Vtb + (size_t)d * 2048 + sv;
  }

#define STAGE_K(buf, kt_)                                                      \
  {                                                                            \
    const int kv0_ = (kt_) * 64;                                               \
    _Pragma("unroll")                                                          \
    for (int i = 0; i < 2; ++i)                                                \
      gload16((char*)Kl + (buf) * 16384 + i * 8192 + tid * 16,                 \
              kSrc[i] + (size_t)kv0_ * DQ);                                    \
  }
#define STAGE_V(kt_)                                                           \
  {                                                                            \
    const int kv0_ = (kt_) * 64;                                               \
    _Pragma("unroll")                                                          \
    for (int i = 0; i < 2; ++i)                                                \
      gload16((char*)Vl + i * 8192 + tid * 16, vSrc[i] + kv0_);                \
  }

  const float scale = 0.08838834764831845f;  // 1/sqrt(128)

  STAGE_K(0, 0);
  STAGE_V(0);

  for (int kt = 0; kt < nt; ++kt) {
    const int cur = kt & 1;
    const int kv0 = kt * 64;
    if (kt + 1 < nt) {
      STAGE_K(cur ^ 1, kt + 1);
      asm volatile("s_waitcnt vmcnt(4)" ::: "memory");  // K(t) landed
    } else {
      asm volatile("s_waitcnt vmcnt(2)" ::: "memory");
    }
    __builtin_amdgcn_s_barrier();

    const char* Kcur = (const char*)Kl + cur * 16384;

    // S^T = K Q^T : sc[n] lane holds q = qrow0+li, keys kv0+n*16+lg*4+j
    floatx4 sc[4];
#pragma unroll
    for (int n = 0; n < 4; ++n) sc[n] = floatx4{0.f, 0.f, 0.f, 0.f};
#pragma unroll
    for (int n = 0; n < 4; ++n) {
      const int r = n * 16 + li;
#pragma unroll
      for (int kk = 0; kk < 4; ++kk) {
        const int byteo = (r * 256 + kk * 64 + lg * 16) ^ ((r & 7) << 4);
        const short8v kf = *(const short8v*)(Kcur + byteo);
        sc[n] = __builtin_amdgcn_mfma_f32_16x16x32_bf16(kf, qb[kk], sc[n], 0, 0, 0);
      }
    }

    ushort4 mfl[4];
#pragma unroll
    for (int n = 0; n < 4; ++n)
      mfl[n] = *(const ushort4*)&msk[kv0 + n * 16 + lg * 4];
    const bool cz = (kt >= causalFromW);

    // softmax (single q-row group per wave)
    const int q_l = qrow0 + li;
    float tmax = -3.0e38f;
#pragma unroll
    for (int n = 0; n < 4; ++n) {
      const u16 fl[4] = {mfl[n].x, mfl[n].y, mfl[n].z, mfl[n].w};
#pragma unroll
      for (int j = 0; j < 4; ++j) {
        float s = sc[n][j] * scale + (fl[j] ? 0.f : -1.0e9f);
        if (cz && (kv0 + n * 16 + lg * 4 + j > q_l)) s -= 1.0e9f;
        sc[n][j] = s;
        tmax = fmaxf(tmax, s);
      }
    }
    tmax = fmaxf(tmax, __shfl_xor(tmax, 16));
    tmax = fmaxf(tmax, __shfl_xor(tmax, 32));
    const float mnew = fmaxf(mM, tmax);
    const float f = __expf(mM - mnew);
    mM = mnew;
    float rs = 0.f;
#pragma unroll
    for (int n = 0; n < 4; ++n)
#pragma unroll
      for (int j = 0; j < 4; ++j) {
        const float e = __expf(sc[n][j] - mnew);
        sc[n][j] = e; rs += e;
      }
    rs += __shfl_xor(rs, 16);
    rs += __shfl_xor(rs, 32);
    lSum = lSum * f + rs;
#pragma unroll
    for (int n2 = 0; n2 < 8; ++n2) oa[n2] *= f;

    // pack P -> PV B-frag via cvt_pk + permlane swaps
    short8v pf[2];
    {
      unsigned w32[4][2];
#pragma unroll
      for (int n = 0; n < 4; ++n) {
        w32[n][0] = cvt_pk_bf16(sc[n][0], sc[n][1]);
        w32[n][1] = cvt_pk_bf16(sc[n][2], sc[n][3]);
      }
      union PF { short8v s; unsigned w[4]; } pfu[2];
#pragma unroll
      for (int kk2 = 0; kk2 < 2; ++kk2) {
#pragma unroll
        for (int hh = 0; hh < 2; ++hh) {
          unsigned u = w32[2 * kk2][hh], v = w32[2 * kk2 + 1][hh];
          asm volatile("v_permlane32_swap_b32 %0, %1" : "+v"(u), "+v"(v));
          asm volatile("v_permlane16_swap_b32 %0, %1" : "+v"(u), "+v"(v));
          pfu[kk2].w[hh] = u;
          pfu[kk2].w[2 + hh] = v;
        }
      }
      pf[0] = pfu[0].s;
      pf[1] = pfu[1].s;
    }

    if (kt + 1 < nt) asm volatile("s_waitcnt vmcnt(2)" ::: "memory");  // V(t) landed
    else             asm volatile("s_waitcnt vmcnt(0)" ::: "memory");
    __builtin_amdgcn_s_barrier();

    // O^T += V^T P^T
#pragma unroll
    for (int kk2 = 0; kk2 < 2; ++kk2) {
#pragma unroll
      for (int n2 = 0; n2 < 8; ++n2) {
        const int d = n2 * 16 + li;
        const int vbyte = (d * 128 + kk2 * 64 + lg * 16) ^ ((d & 7) << 4);
        const short8v vf = *(const short8v*)((const char*)Vl + vbyte);
        oa[n2] = __builtin_amdgcn_mfma_f32_16x16x32_bf16(vf, pf[kk2], oa[n2], 0, 0, 0);
      }
    }
    __builtin_amdgcn_s_barrier();
    if (kt + 1 < nt) STAGE_V(kt + 1);
  }

  // epilogue: oa[n2][j] = O[q=qrow0+li][d=n2*16+lg*4+j]; stage per-wave 4KB in Kl
  {
    char* Ol = (char*)Kl + wave * 4096;   // [16 q][128 d] u16, swizzled
    const float inv = 1.0f / lSum;
#pragma unroll
    for (int n2 = 0; n2 < 8; ++n2) {
      unsigned lo = cvt_pk_bf16(oa[n2][0] * inv, oa[n2][1] * inv);
      unsigned hi = cvt_pk_bf16(oa[n2][2] * inv, oa[n2][3] * inv);
      const int byteo = (li * 256 + n2 * 32 + lg * 8) ^ ((li & 7) << 4);
      uint2 pr2; pr2.x = lo; pr2.y = hi;
      *(uint2*)(Ol + byteo) = pr2;
    }
    asm volatile("s_waitcnt lgkmcnt(0)" ::: "memory");
#pragma unroll
    for (int rr = 0; rr < 4; ++rr) {
      const int r = rr * 4 + lg;
      const size_t grow = (size_t)(b * 2048 + qrow0 + r) * 2048 + h * 128;
      const int byteo = (r * 256 + li * 16) ^ ((r & 7) << 4);
      const u16x8 val = *(const u16x8*)(Ol + byteo);
      *(u16x8*)&attn_out[grow + li * 8] = val;
    }
  }
#undef STAGE_K
#undef STAGE_V
}

// ---------------- launch ----------------
extern "C" void kernel_launch(void* const* d_in, const int* in_sizes, int n_in,
                              void* d_out, int out_size, void* d_ws, size_t ws_size,
                              hipStream_t stream) {
  const float* x    = (const float*)d_in[0];   // [2,2048,2048]
  const int*   kpm  = (const int*)d_in[1];     // [2,2048]
  const float* wqkv = (const float*)d_in[2];   // [6144,2048]
  const float* bqkv = (const float*)d_in[3];   // [6144]
  const float* wout = (const float*)d_in[4];   // [2048,2048]
  const float* bout = (const float*)d_in[5];   // [2048]
  float* out = (float*)d_out;

  char* ws = (char*)d_ws;
  u16* xbf   = (u16*)(ws);                    // 16 MiB: x bf16 [4096,2048]
  u16* wqbf  = (u16*)(ws + (16u << 20));      // 24 MiB: Wqkv bf16 [6144,2048]
  u16* wobf  = (u16*)(ws + (40u << 20));      //  8 MiB: out_w bf16 [2048,2048]
  u16* qkvb  = (u16*)(ws + (48u << 20));      // 48 MiB: qkv bf16 [4096,6144]
  u16* vtb   = (u16*)(ws + (96u << 20));      // 16 MiB: V^T bf16 [32,128,2048]
  u16* attnb = (u16*)(ws + (112u << 20));     // 16 MiB: attn bf16 [4096,2048]

  f2bf_kernel<<<1024, 256, 0, stream>>>(x,    xbf,  4096 * 2048 / 4);
  f2bf_kernel<<<1024, 256, 0, stream>>>(wqkv, wqbf, 6144 * 2048 / 4);
  f2bf_kernel<<<1024, 256, 0, stream>>>(wout, wobf, 2048 * 2048 / 4);

  gemm_v4<1><<<768, 512, 0, stream>>>(xbf, wqbf, bqkv, qkvb, 4096, 6144, 2048);
  transpose_v<<<dim3(32, 32), 256, 0, stream>>>(qkvb, vtb);
  attn_fused<<<dim3(16, 32), 512, 0, stream>>>(qkvb, vtb, kpm, attnb);
  gemm_s<0><<<512, 256, 0, stream>>>(attnb, wobf, bout, out, 4096, 2048, 2048);
}